// Round 5
// baseline (1325.189 us; speedup 1.0000x reference)
//
#include <hip/hip_runtime.h>
#include <hip/hip_bf16.h>

#define N_DIM 128
#define NHEADS 4
#define HEAD_DIM 32

typedef unsigned short bf16_t;

__device__ __forceinline__ float bf16_to_f32(unsigned int u16) {
    union { unsigned int i; float f; } x;
    x.i = u16 << 16;
    return x.f;
}

__device__ __forceinline__ bf16_t f32_to_bf16(float f) {
    union { float f; unsigned int i; } x;
    x.f = f;
    // round-to-nearest-even
    unsigned int r = x.i + 0x7FFFu + ((x.i >> 16) & 1u);
    return (bf16_t)(r >> 16);
}

// ---------------------------------------------------------------------------
// K1: q/k/v = nodes @ W{q,k,v} + b{q,k,v}, stored bf16.
// 8 nodes per block staged in LDS; 32 lanes x float4 output columns.
// ---------------------------------------------------------------------------
__global__ __launch_bounds__(256) void qkv_kernel(
    const float* __restrict__ nodes,
    const float* __restrict__ Wq, const float* __restrict__ bq,
    const float* __restrict__ Wk, const float* __restrict__ bk,
    const float* __restrict__ Wv, const float* __restrict__ bv,
    bf16_t* __restrict__ qb, bf16_t* __restrict__ kb, bf16_t* __restrict__ vb,
    int N)
{
    __shared__ float xs[8 * N_DIM];
    const int tid = threadIdx.x;
    const int nb = blockIdx.x * 8;

    // cooperative load of 8 node rows (8*128 floats = 256 float4)
    ((float4*)xs)[tid] = ((const float4*)(nodes + (size_t)nb * N_DIM))[tid];
    __syncthreads();

    const int nsub = tid >> 5;      // 0..7
    const int lane = tid & 31;      // 0..31
    const int c0 = lane * 4;        // output column group
    const int n = nb + nsub;

    const float* xrow = xs + nsub * N_DIM;
    float4 aq = {0.f, 0.f, 0.f, 0.f};
    float4 ak = {0.f, 0.f, 0.f, 0.f};
    float4 av = {0.f, 0.f, 0.f, 0.f};

#pragma unroll 4
    for (int k = 0; k < N_DIM; ++k) {
        const float x = xrow[k];
        const float4 wq = *(const float4*)(Wq + k * N_DIM + c0);
        const float4 wk = *(const float4*)(Wk + k * N_DIM + c0);
        const float4 wv = *(const float4*)(Wv + k * N_DIM + c0);
        aq.x = fmaf(x, wq.x, aq.x); aq.y = fmaf(x, wq.y, aq.y);
        aq.z = fmaf(x, wq.z, aq.z); aq.w = fmaf(x, wq.w, aq.w);
        ak.x = fmaf(x, wk.x, ak.x); ak.y = fmaf(x, wk.y, ak.y);
        ak.z = fmaf(x, wk.z, ak.z); ak.w = fmaf(x, wk.w, ak.w);
        av.x = fmaf(x, wv.x, av.x); av.y = fmaf(x, wv.y, av.y);
        av.z = fmaf(x, wv.z, av.z); av.w = fmaf(x, wv.w, av.w);
    }

    const float4 b_q = *(const float4*)(bq + c0);
    const float4 b_k = *(const float4*)(bk + c0);
    const float4 b_v = *(const float4*)(bv + c0);

    ushort4 uq, uk, uv;
    uq.x = f32_to_bf16(aq.x + b_q.x); uq.y = f32_to_bf16(aq.y + b_q.y);
    uq.z = f32_to_bf16(aq.z + b_q.z); uq.w = f32_to_bf16(aq.w + b_q.w);
    uk.x = f32_to_bf16(ak.x + b_k.x); uk.y = f32_to_bf16(ak.y + b_k.y);
    uk.z = f32_to_bf16(ak.z + b_k.z); uk.w = f32_to_bf16(ak.w + b_k.w);
    uv.x = f32_to_bf16(av.x + b_v.x); uv.y = f32_to_bf16(av.y + b_v.y);
    uv.z = f32_to_bf16(av.z + b_v.z); uv.w = f32_to_bf16(av.w + b_v.w);

    *(ushort4*)(qb + (size_t)n * N_DIM + c0) = uq;
    *(ushort4*)(kb + (size_t)n * N_DIM + c0) = uk;
    *(ushort4*)(vb + (size_t)n * N_DIM + c0) = uv;
}

// ---------------------------------------------------------------------------
// K2: per-edge head-dot -> softmax over 4 heads -> weighted v scatter-add.
// One wave (64 lanes) per edge; lane l owns elements 2l, 2l+1 (head = l/16).
// ---------------------------------------------------------------------------
__global__ __launch_bounds__(256) void edge_kernel(
    const int* __restrict__ senders, const int* __restrict__ receivers,
    const bf16_t* __restrict__ qb, const bf16_t* __restrict__ kb,
    const bf16_t* __restrict__ vb,
    float* __restrict__ agg, int E)
{
    const int wid = threadIdx.x >> 6;
    const int lane = threadIdx.x & 63;
    const int e = blockIdx.x * 4 + wid;
    if (e >= E) return;

    const int s = senders[e];
    const int r = receivers[e];

    const int c = lane * 2;  // element pair index
    const unsigned int qu = *(const unsigned int*)(qb + (size_t)s * N_DIM + c);
    const unsigned int ku = *(const unsigned int*)(kb + (size_t)r * N_DIM + c);
    const unsigned int vu = *(const unsigned int*)(vb + (size_t)s * N_DIM + c);

    const float qx = bf16_to_f32(qu & 0xffffu), qy = bf16_to_f32(qu >> 16);
    const float kx = bf16_to_f32(ku & 0xffffu), ky = bf16_to_f32(ku >> 16);

    float p = qx * kx + qy * ky;
    // reduce within each 16-lane group (one head per group)
    p += __shfl_xor(p, 1);
    p += __shfl_xor(p, 2);
    p += __shfl_xor(p, 4);
    p += __shfl_xor(p, 8);

    const float scale = 0.17677669529663687f;  // 1/sqrt(32)
    const float s0 = __shfl(p, 0)  * scale;
    const float s1 = __shfl(p, 16) * scale;
    const float s2 = __shfl(p, 32) * scale;
    const float s3 = __shfl(p, 48) * scale;

    const float m = fmaxf(fmaxf(s0, s1), fmaxf(s2, s3));
    const float e0 = __expf(s0 - m);
    const float e1 = __expf(s1 - m);
    const float e2 = __expf(s2 - m);
    const float e3 = __expf(s3 - m);
    const float inv = 1.0f / (e0 + e1 + e2 + e3);

    const int h = lane >> 4;
    const float a = (h == 0 ? e0 : h == 1 ? e1 : h == 2 ? e2 : e3) * inv;

    const float wx = bf16_to_f32(vu & 0xffffu) * a;
    const float wy = bf16_to_f32(vu >> 16) * a;

    float* dst = agg + (size_t)r * N_DIM + c;
    atomicAdd(dst, wx);
    atomicAdd(dst + 1, wy);
}

// ---------------------------------------------------------------------------
// K3: out = agg @ Wo + bo + nodes, in-place on d_out (agg lives in d_out).
// Row-local: each block stages its 8 rows to LDS before overwriting them.
// ---------------------------------------------------------------------------
__global__ __launch_bounds__(256) void out_kernel(
    const float* __restrict__ nodes,
    const float* __restrict__ Wo, const float* __restrict__ bo,
    float* __restrict__ out, int N)
{
    __shared__ float xs[8 * N_DIM];
    const int tid = threadIdx.x;
    const int nb = blockIdx.x * 8;

    ((float4*)xs)[tid] = ((const float4*)(out + (size_t)nb * N_DIM))[tid];
    __syncthreads();

    const int nsub = tid >> 5;
    const int lane = tid & 31;
    const int c0 = lane * 4;
    const int n = nb + nsub;

    const float* xrow = xs + nsub * N_DIM;
    float4 acc = {0.f, 0.f, 0.f, 0.f};

#pragma unroll 4
    for (int k = 0; k < N_DIM; ++k) {
        const float x = xrow[k];
        const float4 w = *(const float4*)(Wo + k * N_DIM + c0);
        acc.x = fmaf(x, w.x, acc.x); acc.y = fmaf(x, w.y, acc.y);
        acc.z = fmaf(x, w.z, acc.z); acc.w = fmaf(x, w.w, acc.w);
    }

    const float4 b = *(const float4*)(bo + c0);
    const float4 nd = *(const float4*)(nodes + (size_t)n * N_DIM + c0);
    float4 res;
    res.x = acc.x + b.x + nd.x;
    res.y = acc.y + b.y + nd.y;
    res.z = acc.z + b.z + nd.z;
    res.w = acc.w + b.w + nd.w;
    *(float4*)(out + (size_t)n * N_DIM + c0) = res;
}

// ---------------------------------------------------------------------------
extern "C" void kernel_launch(void* const* d_in, const int* in_sizes, int n_in,
                              void* d_out, int out_size, void* d_ws, size_t ws_size,
                              hipStream_t stream)
{
    const float* nodes   = (const float*)d_in[0];
    const int* senders   = (const int*)d_in[1];
    const int* receivers = (const int*)d_in[2];
    const float* Wq = (const float*)d_in[3];
    const float* bq = (const float*)d_in[4];
    const float* Wk = (const float*)d_in[5];
    const float* bk = (const float*)d_in[6];
    const float* Wv = (const float*)d_in[7];
    const float* bv = (const float*)d_in[8];
    const float* Wo = (const float*)d_in[9];
    const float* bo = (const float*)d_in[10];

    const int N = in_sizes[0] / N_DIM;   // 100000
    const int E = in_sizes[1];           // 600000

    float* out = (float*)d_out;

    bf16_t* qb = (bf16_t*)d_ws;
    bf16_t* kb = qb + (size_t)N * N_DIM;
    bf16_t* vb = kb + (size_t)N * N_DIM;

    // agg accumulates in d_out; zero it first
    hipMemsetAsync(d_out, 0, (size_t)N * N_DIM * sizeof(float), stream);

    qkv_kernel<<<(N + 7) / 8, 256, 0, stream>>>(
        nodes, Wq, bq, Wk, bk, Wv, bv, qb, kb, vb, N);

    edge_kernel<<<(E + 3) / 4, 256, 0, stream>>>(
        senders, receivers, qb, kb, vb, out, E);

    out_kernel<<<(N + 7) / 8, 256, 0, stream>>>(
        nodes, Wo, bo, out, N);
}

// Round 8
// 707.924 us; speedup vs baseline: 1.8719x; 1.8719x over previous
//
#include <hip/hip_runtime.h>
#include <hip/hip_bf16.h>

#define N_DIM 128
#define NHEADS 4
#define HEAD_DIM 32

typedef unsigned short bf16_t;
typedef short bf16x8 __attribute__((ext_vector_type(8)));
typedef float f32x4 __attribute__((ext_vector_type(4)));

__device__ __forceinline__ float bf16_to_f32(unsigned int u16) {
    union { unsigned int i; float f; } x;
    x.i = u16 << 16;
    return x.f;
}

__device__ __forceinline__ bf16_t f32_to_bf16(float f) {
    union { float f; unsigned int i; } x;
    x.f = f;
    unsigned int r = x.i + 0x7FFFu + ((x.i >> 16) & 1u);  // RNE
    return (bf16_t)(r >> 16);
}

// padded LDS stride for the 32x128 bf16 A-tile: 136 elems = 272 B
// -> per-row bank shift of 4, 16 rows alias only 2-way (free, m136)
#define LDA_STRIDE 136

// ---------------------------------------------------------------------------
// K0: transpose W's to bf16.  Wt[384][128]: rows 0-127 = Wq^T, 128-255 = Wk^T,
// 256-383 = Wv^T.  Wot[128][128] = Wo^T.  (W[k][n] -> Wt[n][k])
// ---------------------------------------------------------------------------
__global__ __launch_bounds__(128) void transpose_w_kernel(
    const float* __restrict__ Wq, const float* __restrict__ Wk,
    const float* __restrict__ Wv, const float* __restrict__ Wo,
    bf16_t* __restrict__ Wt, bf16_t* __restrict__ Wot)
{
    const int n = blockIdx.x;    // 0..511 output row
    const int k = threadIdx.x;   // 0..127
    const float* W; bf16_t* dst; int nl;
    if (n < 128)      { W = Wq; nl = n;       dst = Wt  + n * 128; }
    else if (n < 256) { W = Wk; nl = n - 128; dst = Wt  + n * 128; }
    else if (n < 384) { W = Wv; nl = n - 256; dst = Wt  + n * 128; }
    else              { W = Wo; nl = n - 384; dst = Wot + (n - 384) * 128; }
    dst[k] = f32_to_bf16(W[k * 128 + nl]);
}

// ---------------------------------------------------------------------------
// K1 (MFMA): q/k/v = nodes @ W{q,k,v} + b, stored bf16.
// Block: 256 thr = 4 waves, BM=32 rows.  A-tile (32x128 bf16) in padded LDS.
// Wave w owns n-tiles w*6 .. w*6+5 (N=384 total = 24 tiles of 16).
// mfma_f32_16x16x32_bf16: A row = lane&15, k=(lane>>4)*8+e;
//                          B col = lane&15 (Wt row), same k grouping;
//                          D col = lane&15, row = (lane>>4)*4 + j  (m89).
// ---------------------------------------------------------------------------
__global__ __launch_bounds__(256) void qkv_mfma_kernel(
    const float* __restrict__ nodes,
    const bf16_t* __restrict__ Wt,
    const float* __restrict__ bq, const float* __restrict__ bk,
    const float* __restrict__ bv,
    bf16_t* __restrict__ qb, bf16_t* __restrict__ kb, bf16_t* __restrict__ vb,
    int N)
{
    __shared__ bf16_t lds_a[32 * LDA_STRIDE];
    const int tid = threadIdx.x;
    const int m0 = blockIdx.x * 32;

    // stage 32x128 f32 -> bf16 LDS (1024 float4, 4 per thread)
#pragma unroll
    for (int i = 0; i < 4; ++i) {
        const int f = tid + 256 * i;
        const int row = f >> 5, c4 = f & 31;
        const int g = m0 + row;
        float4 v = make_float4(0.f, 0.f, 0.f, 0.f);
        if (g < N) v = ((const float4*)nodes)[(size_t)g * 32 + c4];
        ushort4 u;
        u.x = f32_to_bf16(v.x); u.y = f32_to_bf16(v.y);
        u.z = f32_to_bf16(v.z); u.w = f32_to_bf16(v.w);
        *(ushort4*)(lds_a + row * LDA_STRIDE + c4 * 4) = u;
    }
    __syncthreads();

    const int w  = tid >> 6;
    const int l  = tid & 63;
    const int lr = l & 15;   // tile row (A) / tile col (B,D)
    const int lg = l >> 4;   // k-group 0..3

    bf16x8 a[2][4];
#pragma unroll
    for (int mt = 0; mt < 2; ++mt)
#pragma unroll
        for (int kt = 0; kt < 4; ++kt)
            a[mt][kt] = *(const bf16x8*)(lds_a + (mt * 16 + lr) * LDA_STRIDE
                                         + kt * 32 + lg * 8);

#pragma unroll
    for (int ni = 0; ni < 6; ++ni) {
        const int nt = w * 6 + ni;          // 0..23
        const int col = nt * 16 + lr;       // 0..383
        f32x4 acc0 = {0.f, 0.f, 0.f, 0.f};
        f32x4 acc1 = {0.f, 0.f, 0.f, 0.f};
#pragma unroll
        for (int kt = 0; kt < 4; ++kt) {
            const bf16x8 b = *(const bf16x8*)(Wt + (size_t)col * 128
                                              + kt * 32 + lg * 8);
            acc0 = __builtin_amdgcn_mfma_f32_16x16x32_bf16(a[0][kt], b, acc0, 0, 0, 0);
            acc1 = __builtin_amdgcn_mfma_f32_16x16x32_bf16(a[1][kt], b, acc1, 0, 0, 0);
        }
        bf16_t* dst; int cl; const float* bias;
        if (nt < 8)       { dst = qb; cl = col;       bias = bq; }
        else if (nt < 16) { dst = kb; cl = col - 128; bias = bk; }
        else              { dst = vb; cl = col - 256; bias = bv; }
        const float bb = bias[cl];
#pragma unroll
        for (int j = 0; j < 4; ++j) {
            const int r0 = m0 + lg * 4 + j;
            if (r0 < N) dst[(size_t)r0 * 128 + cl] = f32_to_bf16(acc0[j] + bb);
            const int r1 = m0 + 16 + lg * 4 + j;
            if (r1 < N) dst[(size_t)r1 * 128 + cl] = f32_to_bf16(acc1[j] + bb);
        }
    }
}

// ---------------------------------------------------------------------------
// K3 (MFMA): out = agg @ Wo + bo + nodes, in-place on d_out (agg in d_out).
// Same structure; N=128 -> 8 n-tiles, wave w owns nt = w*2 + {0,1}.
// ---------------------------------------------------------------------------
__global__ __launch_bounds__(256) void out_mfma_kernel(
    const float* __restrict__ nodes,
    const bf16_t* __restrict__ Wot,
    const float* __restrict__ bo,
    float* __restrict__ out, int N)
{
    __shared__ bf16_t lds_a[32 * LDA_STRIDE];
    const int tid = threadIdx.x;
    const int m0 = blockIdx.x * 32;

#pragma unroll
    for (int i = 0; i < 4; ++i) {
        const int f = tid + 256 * i;
        const int row = f >> 5, c4 = f & 31;
        const int g = m0 + row;
        float4 v = make_float4(0.f, 0.f, 0.f, 0.f);
        if (g < N) v = ((const float4*)out)[(size_t)g * 32 + c4];
        ushort4 u;
        u.x = f32_to_bf16(v.x); u.y = f32_to_bf16(v.y);
        u.z = f32_to_bf16(v.z); u.w = f32_to_bf16(v.w);
        *(ushort4*)(lds_a + row * LDA_STRIDE + c4 * 4) = u;
    }
    __syncthreads();

    const int w  = tid >> 6;
    const int l  = tid & 63;
    const int lr = l & 15;
    const int lg = l >> 4;

    bf16x8 a[2][4];
#pragma unroll
    for (int mt = 0; mt < 2; ++mt)
#pragma unroll
        for (int kt = 0; kt < 4; ++kt)
            a[mt][kt] = *(const bf16x8*)(lds_a + (mt * 16 + lr) * LDA_STRIDE
                                         + kt * 32 + lg * 8);

#pragma unroll
    for (int ni = 0; ni < 2; ++ni) {
        const int nt = w * 2 + ni;          // 0..7
        const int col = nt * 16 + lr;       // 0..127
        f32x4 acc0 = {0.f, 0.f, 0.f, 0.f};
        f32x4 acc1 = {0.f, 0.f, 0.f, 0.f};
#pragma unroll
        for (int kt = 0; kt < 4; ++kt) {
            const bf16x8 b = *(const bf16x8*)(Wot + (size_t)col * 128
                                              + kt * 32 + lg * 8);
            acc0 = __builtin_amdgcn_mfma_f32_16x16x32_bf16(a[0][kt], b, acc0, 0, 0, 0);
            acc1 = __builtin_amdgcn_mfma_f32_16x16x32_bf16(a[1][kt], b, acc1, 0, 0, 0);
        }
        const float bb = bo[col];
#pragma unroll
        for (int j = 0; j < 4; ++j) {
            const int r0 = m0 + lg * 4 + j;
            if (r0 < N)
                out[(size_t)r0 * 128 + col] =
                    acc0[j] + bb + nodes[(size_t)r0 * 128 + col];
            const int r1 = m0 + 16 + lg * 4 + j;
            if (r1 < N)
                out[(size_t)r1 * 128 + col] =
                    acc1[j] + bb + nodes[(size_t)r1 * 128 + col];
        }
    }
}

// ---------------------------------------------------------------------------
// K2: per-edge head-dot -> softmax over 4 heads -> weighted v scatter-add.
// (unchanged this round — awaiting its own counters)
// ---------------------------------------------------------------------------
__global__ __launch_bounds__(256) void edge_kernel(
    const int* __restrict__ senders, const int* __restrict__ receivers,
    const bf16_t* __restrict__ qb, const bf16_t* __restrict__ kb,
    const bf16_t* __restrict__ vb,
    float* __restrict__ agg, int E)
{
    const int wid = threadIdx.x >> 6;
    const int lane = threadIdx.x & 63;
    const int e = blockIdx.x * 4 + wid;
    if (e >= E) return;

    const int s = senders[e];
    const int r = receivers[e];

    const int c = lane * 2;
    const unsigned int qu = *(const unsigned int*)(qb + (size_t)s * N_DIM + c);
    const unsigned int ku = *(const unsigned int*)(kb + (size_t)r * N_DIM + c);
    const unsigned int vu = *(const unsigned int*)(vb + (size_t)s * N_DIM + c);

    const float qx = bf16_to_f32(qu & 0xffffu), qy = bf16_to_f32(qu >> 16);
    const float kx = bf16_to_f32(ku & 0xffffu), ky = bf16_to_f32(ku >> 16);

    float p = qx * kx + qy * ky;
    p += __shfl_xor(p, 1);
    p += __shfl_xor(p, 2);
    p += __shfl_xor(p, 4);
    p += __shfl_xor(p, 8);

    const float scale = 0.17677669529663687f;  // 1/sqrt(32)
    const float s0 = __shfl(p, 0)  * scale;
    const float s1 = __shfl(p, 16) * scale;
    const float s2 = __shfl(p, 32) * scale;
    const float s3 = __shfl(p, 48) * scale;

    const float m = fmaxf(fmaxf(s0, s1), fmaxf(s2, s3));
    const float e0 = __expf(s0 - m);
    const float e1 = __expf(s1 - m);
    const float e2 = __expf(s2 - m);
    const float e3 = __expf(s3 - m);
    const float inv = 1.0f / (e0 + e1 + e2 + e3);

    const int h = lane >> 4;
    const float aw = (h == 0 ? e0 : h == 1 ? e1 : h == 2 ? e2 : e3) * inv;

    const float wx = bf16_to_f32(vu & 0xffffu) * aw;
    const float wy = bf16_to_f32(vu >> 16) * aw;

    float* dst = agg + (size_t)r * N_DIM + c;
    atomicAdd(dst, wx);
    atomicAdd(dst + 1, wy);
}

// ---------------------------------------------------------------------------
// Fallback VALU projections (measured-correct path, used only if ws too small)
// ---------------------------------------------------------------------------
__global__ __launch_bounds__(256) void qkv_kernel(
    const float* __restrict__ nodes,
    const float* __restrict__ Wq, const float* __restrict__ bq,
    const float* __restrict__ Wk, const float* __restrict__ bk,
    const float* __restrict__ Wv, const float* __restrict__ bv,
    bf16_t* __restrict__ qb, bf16_t* __restrict__ kb, bf16_t* __restrict__ vb,
    int N)
{
    __shared__ float xs[8 * N_DIM];
    const int tid = threadIdx.x;
    const int nb = blockIdx.x * 8;

    ((float4*)xs)[tid] = ((const float4*)(nodes + (size_t)nb * N_DIM))[tid];
    __syncthreads();

    const int nsub = tid >> 5;
    const int lane = tid & 31;
    const int c0 = lane * 4;
    const int n = nb + nsub;

    const float* xrow = xs + nsub * N_DIM;
    float4 aq = {0.f, 0.f, 0.f, 0.f};
    float4 ak = {0.f, 0.f, 0.f, 0.f};
    float4 av = {0.f, 0.f, 0.f, 0.f};

#pragma unroll 4
    for (int k = 0; k < N_DIM; ++k) {
        const float x = xrow[k];
        const float4 wq = *(const float4*)(Wq + k * N_DIM + c0);
        const float4 wk = *(const float4*)(Wk + k * N_DIM + c0);
        const float4 wv = *(const float4*)(Wv + k * N_DIM + c0);
        aq.x = fmaf(x, wq.x, aq.x); aq.y = fmaf(x, wq.y, aq.y);
        aq.z = fmaf(x, wq.z, aq.z); aq.w = fmaf(x, wq.w, aq.w);
        ak.x = fmaf(x, wk.x, ak.x); ak.y = fmaf(x, wk.y, ak.y);
        ak.z = fmaf(x, wk.z, ak.z); ak.w = fmaf(x, wk.w, ak.w);
        av.x = fmaf(x, wv.x, av.x); av.y = fmaf(x, wv.y, av.y);
        av.z = fmaf(x, wv.z, av.z); av.w = fmaf(x, wv.w, av.w);
    }

    const float4 b_q = *(const float4*)(bq + c0);
    const float4 b_k = *(const float4*)(bk + c0);
    const float4 b_v = *(const float4*)(bv + c0);

    ushort4 uq, uk, uv;
    uq.x = f32_to_bf16(aq.x + b_q.x); uq.y = f32_to_bf16(aq.y + b_q.y);
    uq.z = f32_to_bf16(aq.z + b_q.z); uq.w = f32_to_bf16(aq.w + b_q.w);
    uk.x = f32_to_bf16(ak.x + b_k.x); uk.y = f32_to_bf16(ak.y + b_k.y);
    uk.z = f32_to_bf16(ak.z + b_k.z); uk.w = f32_to_bf16(ak.w + b_k.w);
    uv.x = f32_to_bf16(av.x + b_v.x); uv.y = f32_to_bf16(av.y + b_v.y);
    uv.z = f32_to_bf16(av.z + b_v.z); uv.w = f32_to_bf16(av.w + b_v.w);

    *(ushort4*)(qb + (size_t)n * N_DIM + c0) = uq;
    *(ushort4*)(kb + (size_t)n * N_DIM + c0) = uk;
    *(ushort4*)(vb + (size_t)n * N_DIM + c0) = uv;
}

__global__ __launch_bounds__(256) void out_kernel(
    const float* __restrict__ nodes,
    const float* __restrict__ Wo, const float* __restrict__ bo,
    float* __restrict__ out, int N)
{
    __shared__ float xs[8 * N_DIM];
    const int tid = threadIdx.x;
    const int nb = blockIdx.x * 8;

    ((float4*)xs)[tid] = ((const float4*)(out + (size_t)nb * N_DIM))[tid];
    __syncthreads();

    const int nsub = tid >> 5;
    const int lane = tid & 31;
    const int c0 = lane * 4;
    const int n = nb + nsub;

    const float* xrow = xs + nsub * N_DIM;
    float4 acc = {0.f, 0.f, 0.f, 0.f};

#pragma unroll 4
    for (int k = 0; k < N_DIM; ++k) {
        const float x = xrow[k];
        const float4 wv = *(const float4*)(Wo + k * N_DIM + c0);
        acc.x = fmaf(x, wv.x, acc.x); acc.y = fmaf(x, wv.y, acc.y);
        acc.z = fmaf(x, wv.z, acc.z); acc.w = fmaf(x, wv.w, acc.w);
    }

    const float4 b = *(const float4*)(bo + c0);
    const float4 nd = *(const float4*)(nodes + (size_t)n * N_DIM + c0);
    float4 res;
    res.x = acc.x + b.x + nd.x;
    res.y = acc.y + b.y + nd.y;
    res.z = acc.z + b.z + nd.z;
    res.w = acc.w + b.w + nd.w;
    *(float4*)(out + (size_t)n * N_DIM + c0) = res;
}

// ---------------------------------------------------------------------------
extern "C" void kernel_launch(void* const* d_in, const int* in_sizes, int n_in,
                              void* d_out, int out_size, void* d_ws, size_t ws_size,
                              hipStream_t stream)
{
    const float* nodes   = (const float*)d_in[0];
    const int* senders   = (const int*)d_in[1];
    const int* receivers = (const int*)d_in[2];
    const float* Wq = (const float*)d_in[3];
    const float* bq = (const float*)d_in[4];
    const float* Wk = (const float*)d_in[5];
    const float* bk = (const float*)d_in[6];
    const float* Wv = (const float*)d_in[7];
    const float* bv = (const float*)d_in[8];
    const float* Wo = (const float*)d_in[9];
    const float* bo = (const float*)d_in[10];

    const int N = in_sizes[0] / N_DIM;   // 100000
    const int E = in_sizes[1];           // 600000

    float* out = (float*)d_out;

    const size_t qkv_bytes = (size_t)N * N_DIM * sizeof(bf16_t);
    bf16_t* qb = (bf16_t*)d_ws;
    bf16_t* kb = qb + (size_t)N * N_DIM;
    bf16_t* vb = kb + (size_t)N * N_DIM;
    bf16_t* Wt  = vb + (size_t)N * N_DIM;          // [384][128] bf16
    bf16_t* Wot = Wt + 384 * 128;                  // [128][128] bf16
    const size_t need = 3 * qkv_bytes + (384 + 128) * 128 * sizeof(bf16_t);

    // agg accumulates in d_out; zero it first
    hipMemsetAsync(d_out, 0, (size_t)N * N_DIM * sizeof(float), stream);

    if (ws_size >= need) {
        transpose_w_kernel<<<512, 128, 0, stream>>>(Wq, Wk, Wv, Wo, Wt, Wot);
        qkv_mfma_kernel<<<(N + 31) / 32, 256, 0, stream>>>(
            nodes, Wt, bq, bk, bv, qb, kb, vb, N);
        edge_kernel<<<(E + 3) / 4, 256, 0, stream>>>(
            senders, receivers, qb, kb, vb, out, E);
        out_mfma_kernel<<<(N + 31) / 32, 256, 0, stream>>>(
            nodes, Wot, bo, out, N);
    } else {
        qkv_kernel<<<(N + 7) / 8, 256, 0, stream>>>(
            nodes, Wq, bq, Wk, bk, Wv, bv, qb, kb, vb, N);
        edge_kernel<<<(E + 3) / 4, 256, 0, stream>>>(
            senders, receivers, qb, kb, vb, out, E);
        out_kernel<<<(N + 7) / 8, 256, 0, stream>>>(
            nodes, Wo, bo, out, N);
    }
}

// Round 9
// 356.752 us; speedup vs baseline: 3.7146x; 1.9844x over previous
//
#include <hip/hip_runtime.h>
#include <hip/hip_bf16.h>

#define N_DIM 128
#define NHEADS 4
#define HEAD_DIM 32

typedef unsigned short bf16_t;
typedef short bf16x8 __attribute__((ext_vector_type(8)));
typedef float f32x4 __attribute__((ext_vector_type(4)));

__device__ __forceinline__ float bf16_to_f32(unsigned int u16) {
    union { unsigned int i; float f; } x;
    x.i = u16 << 16;
    return x.f;
}

__device__ __forceinline__ bf16_t f32_to_bf16(float f) {
    union { float f; unsigned int i; } x;
    x.f = f;
    unsigned int r = x.i + 0x7FFFu + ((x.i >> 16) & 1u);  // RNE
    return (bf16_t)(r >> 16);
}

// padded LDS stride for the 32x128 bf16 A-tile: 136 elems = 272 B
#define LDA_STRIDE 136

// ---------------------------------------------------------------------------
// K0: transpose W's to bf16.  Wt[384][128] = {Wq^T,Wk^T,Wv^T}, Wot = Wo^T.
// ---------------------------------------------------------------------------
__global__ __launch_bounds__(128) void transpose_w_kernel(
    const float* __restrict__ Wq, const float* __restrict__ Wk,
    const float* __restrict__ Wv, const float* __restrict__ Wo,
    bf16_t* __restrict__ Wt, bf16_t* __restrict__ Wot)
{
    const int n = blockIdx.x;    // 0..511
    const int k = threadIdx.x;   // 0..127
    const float* W; bf16_t* dst; int nl;
    if (n < 128)      { W = Wq; nl = n;       dst = Wt  + n * 128; }
    else if (n < 256) { W = Wk; nl = n - 128; dst = Wt  + n * 128; }
    else if (n < 384) { W = Wv; nl = n - 256; dst = Wt  + n * 128; }
    else              { W = Wo; nl = n - 384; dst = Wot + (n - 384) * 128; }
    dst[k] = f32_to_bf16(W[k * 128 + nl]);
}

// ---------------------------------------------------------------------------
// K1 (MFMA): q/k/v projections, bf16 out.  (measured-good, unchanged)
// ---------------------------------------------------------------------------
__global__ __launch_bounds__(256) void qkv_mfma_kernel(
    const float* __restrict__ nodes,
    const bf16_t* __restrict__ Wt,
    const float* __restrict__ bq, const float* __restrict__ bk,
    const float* __restrict__ bv,
    bf16_t* __restrict__ qb, bf16_t* __restrict__ kb, bf16_t* __restrict__ vb,
    int N)
{
    __shared__ bf16_t lds_a[32 * LDA_STRIDE];
    const int tid = threadIdx.x;
    const int m0 = blockIdx.x * 32;

#pragma unroll
    for (int i = 0; i < 4; ++i) {
        const int f = tid + 256 * i;
        const int row = f >> 5, c4 = f & 31;
        const int g = m0 + row;
        float4 v = make_float4(0.f, 0.f, 0.f, 0.f);
        if (g < N) v = ((const float4*)nodes)[(size_t)g * 32 + c4];
        ushort4 u;
        u.x = f32_to_bf16(v.x); u.y = f32_to_bf16(v.y);
        u.z = f32_to_bf16(v.z); u.w = f32_to_bf16(v.w);
        *(ushort4*)(lds_a + row * LDA_STRIDE + c4 * 4) = u;
    }
    __syncthreads();

    const int w  = tid >> 6;
    const int l  = tid & 63;
    const int lr = l & 15;
    const int lg = l >> 4;

    bf16x8 a[2][4];
#pragma unroll
    for (int mt = 0; mt < 2; ++mt)
#pragma unroll
        for (int kt = 0; kt < 4; ++kt)
            a[mt][kt] = *(const bf16x8*)(lds_a + (mt * 16 + lr) * LDA_STRIDE
                                         + kt * 32 + lg * 8);

#pragma unroll
    for (int ni = 0; ni < 6; ++ni) {
        const int nt = w * 6 + ni;
        const int col = nt * 16 + lr;
        f32x4 acc0 = {0.f, 0.f, 0.f, 0.f};
        f32x4 acc1 = {0.f, 0.f, 0.f, 0.f};
#pragma unroll
        for (int kt = 0; kt < 4; ++kt) {
            const bf16x8 b = *(const bf16x8*)(Wt + (size_t)col * 128
                                              + kt * 32 + lg * 8);
            acc0 = __builtin_amdgcn_mfma_f32_16x16x32_bf16(a[0][kt], b, acc0, 0, 0, 0);
            acc1 = __builtin_amdgcn_mfma_f32_16x16x32_bf16(a[1][kt], b, acc1, 0, 0, 0);
        }
        bf16_t* dst; int cl; const float* bias;
        if (nt < 8)       { dst = qb; cl = col;       bias = bq; }
        else if (nt < 16) { dst = kb; cl = col - 128; bias = bk; }
        else              { dst = vb; cl = col - 256; bias = bv; }
        const float bb = bias[cl];
#pragma unroll
        for (int j = 0; j < 4; ++j) {
            const int r0 = m0 + lg * 4 + j;
            if (r0 < N) dst[(size_t)r0 * 128 + cl] = f32_to_bf16(acc0[j] + bb);
            const int r1 = m0 + 16 + lg * 4 + j;
            if (r1 < N) dst[(size_t)r1 * 128 + cl] = f32_to_bf16(acc1[j] + bb);
        }
    }
}

// ---------------------------------------------------------------------------
// CSR build: histogram -> 2-level exclusive scan -> scatter
// ---------------------------------------------------------------------------
__global__ __launch_bounds__(256) void hist_kernel(
    const int* __restrict__ receivers, int* __restrict__ cnt, int E)
{
    const int i = blockIdx.x * 256 + threadIdx.x;
    if (i < E) atomicAdd(&cnt[receivers[i]], 1);
}

// each block scans 1024 elements (4 per thread)
__global__ __launch_bounds__(256) void scan_block_kernel(
    const int* __restrict__ cnt, int* __restrict__ starts,
    int* __restrict__ bsum, int N)
{
    __shared__ int sc[256];
    const int t = threadIdx.x;
    const int base = blockIdx.x * 1024 + t * 4;
    int v0 = (base + 0 < N) ? cnt[base + 0] : 0;
    int v1 = (base + 1 < N) ? cnt[base + 1] : 0;
    int v2 = (base + 2 < N) ? cnt[base + 2] : 0;
    int v3 = (base + 3 < N) ? cnt[base + 3] : 0;
    const int s = v0 + v1 + v2 + v3;
    sc[t] = s;
    __syncthreads();
    for (int off = 1; off < 256; off <<= 1) {
        int x = (t >= off) ? sc[t - off] : 0;
        __syncthreads();
        sc[t] += x;
        __syncthreads();
    }
    int excl = sc[t] - s;
    if (base + 0 < N) starts[base + 0] = excl;
    if (base + 1 < N) starts[base + 1] = excl + v0;
    if (base + 2 < N) starts[base + 2] = excl + v0 + v1;
    if (base + 3 < N) starts[base + 3] = excl + v0 + v1 + v2;
    if (t == 255) bsum[blockIdx.x] = sc[255];
}

// single block scans up to 256 block sums; writes grand total to starts[N]
__global__ __launch_bounds__(256) void scan_top_kernel(
    const int* __restrict__ bsum, int* __restrict__ boff,
    int* __restrict__ starts, int nb, int N)
{
    __shared__ int sc[256];
    const int t = threadIdx.x;
    const int s = (t < nb) ? bsum[t] : 0;
    sc[t] = s;
    __syncthreads();
    for (int off = 1; off < 256; off <<= 1) {
        int x = (t >= off) ? sc[t - off] : 0;
        __syncthreads();
        sc[t] += x;
        __syncthreads();
    }
    if (t < nb) boff[t] = sc[t] - s;
    if (t == 255) starts[N] = sc[255];
}

__global__ __launch_bounds__(256) void scan_add_kernel(
    int* __restrict__ starts, int* __restrict__ cursor,
    const int* __restrict__ boff, int N)
{
    const int t = threadIdx.x;
    const int base = blockIdx.x * 1024 + t * 4;
    const int o = boff[blockIdx.x];
#pragma unroll
    for (int k = 0; k < 4; ++k) {
        const int i = base + k;
        if (i < N) {
            const int v = starts[i] + o;
            starts[i] = v;
            cursor[i] = v;
        }
    }
}

__global__ __launch_bounds__(256) void scatter_kernel(
    const int* __restrict__ senders, const int* __restrict__ receivers,
    int* __restrict__ cursor, int* __restrict__ elist, int E)
{
    const int i = blockIdx.x * 256 + threadIdx.x;
    if (i < E) {
        const int pos = atomicAdd(&cursor[receivers[i]], 1);
        elist[pos] = senders[i];
    }
}

// ---------------------------------------------------------------------------
// K2 (CSR aggregate): one wave per receiver.  k_r in registers; per edge:
// gather q_s/v_s pair, 16-lane head dot, head-softmax, accumulate f32.
// Writes agg row once as bf16 (same rounding point as old path).  No atomics.
// ---------------------------------------------------------------------------
__global__ __launch_bounds__(256) void agg_kernel(
    const int* __restrict__ starts, const int* __restrict__ elist,
    const bf16_t* __restrict__ qb, const bf16_t* __restrict__ kb,
    const bf16_t* __restrict__ vb,
    bf16_t* __restrict__ agg_b, int N)
{
    const int r = blockIdx.x * 4 + (threadIdx.x >> 6);
    const int lane = threadIdx.x & 63;
    if (r >= N) return;

    const int start = starts[r];
    const int end   = starts[r + 1];
    const int c = lane * 2;

    const unsigned int ku = *(const unsigned int*)(kb + (size_t)r * N_DIM + c);
    const float kx = bf16_to_f32(ku & 0xffffu), ky = bf16_to_f32(ku >> 16);

    float ax = 0.f, ay = 0.f;
    const float scale = 0.17677669529663687f;  // 1/sqrt(32)
    const int h = lane >> 4;

    for (int j0 = start; j0 < end; j0 += 64) {
        const int ids = (j0 + lane < end) ? elist[j0 + lane] : 0;
        const int jm = min(64, end - j0);
        for (int j = 0; j < jm; ++j) {
            const int s = __shfl(ids, j);
            const unsigned int qu =
                *(const unsigned int*)(qb + (size_t)s * N_DIM + c);
            const unsigned int vu =
                *(const unsigned int*)(vb + (size_t)s * N_DIM + c);
            const float qx = bf16_to_f32(qu & 0xffffu), qy = bf16_to_f32(qu >> 16);

            float p = qx * kx + qy * ky;
            p += __shfl_xor(p, 1);
            p += __shfl_xor(p, 2);
            p += __shfl_xor(p, 4);
            p += __shfl_xor(p, 8);

            const float s0 = __shfl(p, 0)  * scale;
            const float s1 = __shfl(p, 16) * scale;
            const float s2 = __shfl(p, 32) * scale;
            const float s3 = __shfl(p, 48) * scale;

            const float m = fmaxf(fmaxf(s0, s1), fmaxf(s2, s3));
            const float e0 = __expf(s0 - m);
            const float e1 = __expf(s1 - m);
            const float e2 = __expf(s2 - m);
            const float e3 = __expf(s3 - m);
            const float inv = 1.0f / (e0 + e1 + e2 + e3);
            const float aw = (h == 0 ? e0 : h == 1 ? e1 : h == 2 ? e2 : e3) * inv;

            ax = fmaf(bf16_to_f32(vu & 0xffffu), aw, ax);
            ay = fmaf(bf16_to_f32(vu >> 16),     aw, ay);
        }
    }

    const unsigned int packed =
        (unsigned int)f32_to_bf16(ax) | ((unsigned int)f32_to_bf16(ay) << 16);
    *(unsigned int*)(agg_b + (size_t)r * N_DIM + c) = packed;
}

// ---------------------------------------------------------------------------
// K3 (MFMA): out = agg_b @ Wo + bo + nodes.  Stages bf16 agg directly.
// ---------------------------------------------------------------------------
__global__ __launch_bounds__(256) void out_mfma_b_kernel(
    const float* __restrict__ nodes,
    const bf16_t* __restrict__ agg_b,
    const bf16_t* __restrict__ Wot,
    const float* __restrict__ bo,
    float* __restrict__ out, int N)
{
    __shared__ bf16_t lds_a[32 * LDA_STRIDE];
    const int tid = threadIdx.x;
    const int m0 = blockIdx.x * 32;

#pragma unroll
    for (int i = 0; i < 4; ++i) {
        const int f = tid + 256 * i;
        const int row = f >> 5, c4 = f & 31;
        const int g = m0 + row;
        ushort4 u = make_ushort4(0, 0, 0, 0);
        if (g < N) u = ((const ushort4*)(agg_b + (size_t)g * N_DIM))[c4];
        *(ushort4*)(lds_a + row * LDA_STRIDE + c4 * 4) = u;
    }
    __syncthreads();

    const int w  = tid >> 6;
    const int l  = tid & 63;
    const int lr = l & 15;
    const int lg = l >> 4;

    bf16x8 a[2][4];
#pragma unroll
    for (int mt = 0; mt < 2; ++mt)
#pragma unroll
        for (int kt = 0; kt < 4; ++kt)
            a[mt][kt] = *(const bf16x8*)(lds_a + (mt * 16 + lr) * LDA_STRIDE
                                         + kt * 32 + lg * 8);

#pragma unroll
    for (int ni = 0; ni < 2; ++ni) {
        const int nt = w * 2 + ni;
        const int col = nt * 16 + lr;
        f32x4 acc0 = {0.f, 0.f, 0.f, 0.f};
        f32x4 acc1 = {0.f, 0.f, 0.f, 0.f};
#pragma unroll
        for (int kt = 0; kt < 4; ++kt) {
            const bf16x8 b = *(const bf16x8*)(Wot + (size_t)col * 128
                                              + kt * 32 + lg * 8);
            acc0 = __builtin_amdgcn_mfma_f32_16x16x32_bf16(a[0][kt], b, acc0, 0, 0, 0);
            acc1 = __builtin_amdgcn_mfma_f32_16x16x32_bf16(a[1][kt], b, acc1, 0, 0, 0);
        }
        const float bb = bo[col];
#pragma unroll
        for (int j = 0; j < 4; ++j) {
            const int r0 = m0 + lg * 4 + j;
            if (r0 < N)
                out[(size_t)r0 * 128 + col] =
                    acc0[j] + bb + nodes[(size_t)r0 * 128 + col];
            const int r1 = m0 + 16 + lg * 4 + j;
            if (r1 < N)
                out[(size_t)r1 * 128 + col] =
                    acc1[j] + bb + nodes[(size_t)r1 * 128 + col];
        }
    }
}

// ---------------------------------------------------------------------------
// Fallback kernels (measured-correct paths, used only if ws too small)
// ---------------------------------------------------------------------------
__global__ __launch_bounds__(256) void edge_kernel(
    const int* __restrict__ senders, const int* __restrict__ receivers,
    const bf16_t* __restrict__ qb, const bf16_t* __restrict__ kb,
    const bf16_t* __restrict__ vb,
    float* __restrict__ agg, int E)
{
    const int wid = threadIdx.x >> 6;
    const int lane = threadIdx.x & 63;
    const int e = blockIdx.x * 4 + wid;
    if (e >= E) return;

    const int s = senders[e];
    const int r = receivers[e];

    const int c = lane * 2;
    const unsigned int qu = *(const unsigned int*)(qb + (size_t)s * N_DIM + c);
    const unsigned int ku = *(const unsigned int*)(kb + (size_t)r * N_DIM + c);
    const unsigned int vu = *(const unsigned int*)(vb + (size_t)s * N_DIM + c);

    const float qx = bf16_to_f32(qu & 0xffffu), qy = bf16_to_f32(qu >> 16);
    const float kx = bf16_to_f32(ku & 0xffffu), ky = bf16_to_f32(ku >> 16);

    float p = qx * kx + qy * ky;
    p += __shfl_xor(p, 1);
    p += __shfl_xor(p, 2);
    p += __shfl_xor(p, 4);
    p += __shfl_xor(p, 8);

    const float scale = 0.17677669529663687f;
    const float s0 = __shfl(p, 0)  * scale;
    const float s1 = __shfl(p, 16) * scale;
    const float s2 = __shfl(p, 32) * scale;
    const float s3 = __shfl(p, 48) * scale;

    const float m = fmaxf(fmaxf(s0, s1), fmaxf(s2, s3));
    const float e0 = __expf(s0 - m);
    const float e1 = __expf(s1 - m);
    const float e2 = __expf(s2 - m);
    const float e3 = __expf(s3 - m);
    const float inv = 1.0f / (e0 + e1 + e2 + e3);

    const int h = lane >> 4;
    const float aw = (h == 0 ? e0 : h == 1 ? e1 : h == 2 ? e2 : e3) * inv;

    const float wx = bf16_to_f32(vu & 0xffffu) * aw;
    const float wy = bf16_to_f32(vu >> 16) * aw;

    float* dst = agg + (size_t)r * N_DIM + c;
    atomicAdd(dst, wx);
    atomicAdd(dst + 1, wy);
}

__global__ __launch_bounds__(256) void out_mfma_kernel(
    const float* __restrict__ nodes,
    const bf16_t* __restrict__ Wot,
    const float* __restrict__ bo,
    float* __restrict__ out, int N)
{
    __shared__ bf16_t lds_a[32 * LDA_STRIDE];
    const int tid = threadIdx.x;
    const int m0 = blockIdx.x * 32;

#pragma unroll
    for (int i = 0; i < 4; ++i) {
        const int f = tid + 256 * i;
        const int row = f >> 5, c4 = f & 31;
        const int g = m0 + row;
        float4 v = make_float4(0.f, 0.f, 0.f, 0.f);
        if (g < N) v = ((const float4*)out)[(size_t)g * 32 + c4];
        ushort4 u;
        u.x = f32_to_bf16(v.x); u.y = f32_to_bf16(v.y);
        u.z = f32_to_bf16(v.z); u.w = f32_to_bf16(v.w);
        *(ushort4*)(lds_a + row * LDA_STRIDE + c4 * 4) = u;
    }
    __syncthreads();

    const int w  = tid >> 6;
    const int l  = tid & 63;
    const int lr = l & 15;
    const int lg = l >> 4;

    bf16x8 a[2][4];
#pragma unroll
    for (int mt = 0; mt < 2; ++mt)
#pragma unroll
        for (int kt = 0; kt < 4; ++kt)
            a[mt][kt] = *(const bf16x8*)(lds_a + (mt * 16 + lr) * LDA_STRIDE
                                         + kt * 32 + lg * 8);

#pragma unroll
    for (int ni = 0; ni < 2; ++ni) {
        const int nt = w * 2 + ni;
        const int col = nt * 16 + lr;
        f32x4 acc0 = {0.f, 0.f, 0.f, 0.f};
        f32x4 acc1 = {0.f, 0.f, 0.f, 0.f};
#pragma unroll
        for (int kt = 0; kt < 4; ++kt) {
            const bf16x8 b = *(const bf16x8*)(Wot + (size_t)col * 128
                                              + kt * 32 + lg * 8);
            acc0 = __builtin_amdgcn_mfma_f32_16x16x32_bf16(a[0][kt], b, acc0, 0, 0, 0);
            acc1 = __builtin_amdgcn_mfma_f32_16x16x32_bf16(a[1][kt], b, acc1, 0, 0, 0);
        }
        const float bb = bo[col];
#pragma unroll
        for (int j = 0; j < 4; ++j) {
            const int r0 = m0 + lg * 4 + j;
            if (r0 < N)
                out[(size_t)r0 * 128 + col] =
                    acc0[j] + bb + nodes[(size_t)r0 * 128 + col];
            const int r1 = m0 + 16 + lg * 4 + j;
            if (r1 < N)
                out[(size_t)r1 * 128 + col] =
                    acc1[j] + bb + nodes[(size_t)r1 * 128 + col];
        }
    }
}

// ---------------------------------------------------------------------------
extern "C" void kernel_launch(void* const* d_in, const int* in_sizes, int n_in,
                              void* d_out, int out_size, void* d_ws, size_t ws_size,
                              hipStream_t stream)
{
    const float* nodes   = (const float*)d_in[0];
    const int* senders   = (const int*)d_in[1];
    const int* receivers = (const int*)d_in[2];
    const float* Wq = (const float*)d_in[3];
    const float* bq = (const float*)d_in[4];
    const float* Wk = (const float*)d_in[5];
    const float* bk = (const float*)d_in[6];
    const float* Wv = (const float*)d_in[7];
    const float* bv = (const float*)d_in[8];
    const float* Wo = (const float*)d_in[9];
    const float* bo = (const float*)d_in[10];

    const int N = in_sizes[0] / N_DIM;   // 100000
    const int E = in_sizes[1];           // 600000

    float* out = (float*)d_out;
    char* ws = (char*)d_ws;

    const size_t row_bytes = (size_t)N * N_DIM * sizeof(bf16_t);
    size_t off = 0;
    bf16_t* qb    = (bf16_t*)(ws + off); off += row_bytes;
    bf16_t* kb    = (bf16_t*)(ws + off); off += row_bytes;
    bf16_t* vb    = (bf16_t*)(ws + off); off += row_bytes;
    bf16_t* Wt    = (bf16_t*)(ws + off); off += 384 * 128 * sizeof(bf16_t);
    bf16_t* Wot   = (bf16_t*)(ws + off); off += 128 * 128 * sizeof(bf16_t);
    bf16_t* agg_b = (bf16_t*)(ws + off); off += row_bytes;
    int* cnt      = (int*)(ws + off);    off += (size_t)N * 4;
    int* starts   = (int*)(ws + off);    off += (size_t)(N + 1) * 4;
    int* cursor   = (int*)(ws + off);    off += (size_t)N * 4;
    int* elist    = (int*)(ws + off);    off += (size_t)E * 4;
    int* bsum     = (int*)(ws + off);    off += 256 * 4;
    int* boff     = (int*)(ws + off);    off += 256 * 4;
    const size_t need_csr = off;
    const size_t need_mid = 3 * row_bytes + (384 + 128) * 128 * sizeof(bf16_t);

    const int nb = (N + 1023) / 1024;    // scan blocks (98 for N=100000)

    if (ws_size >= need_csr && nb <= 256) {
        transpose_w_kernel<<<512, 128, 0, stream>>>(Wq, Wk, Wv, Wo, Wt, Wot);
        qkv_mfma_kernel<<<(N + 31) / 32, 256, 0, stream>>>(
            nodes, Wt, bq, bk, bv, qb, kb, vb, N);

        hipMemsetAsync(cnt, 0, (size_t)N * 4, stream);
        hist_kernel<<<(E + 255) / 256, 256, 0, stream>>>(receivers, cnt, E);
        scan_block_kernel<<<nb, 256, 0, stream>>>(cnt, starts, bsum, N);
        scan_top_kernel<<<1, 256, 0, stream>>>(bsum, boff, starts, nb, N);
        scan_add_kernel<<<nb, 256, 0, stream>>>(starts, cursor, boff, N);
        scatter_kernel<<<(E + 255) / 256, 256, 0, stream>>>(
            senders, receivers, cursor, elist, E);

        agg_kernel<<<(N + 3) / 4, 256, 0, stream>>>(
            starts, elist, qb, kb, vb, agg_b, N);

        out_mfma_b_kernel<<<(N + 31) / 32, 256, 0, stream>>>(
            nodes, agg_b, Wot, bo, out, N);
    } else if (ws_size >= need_mid) {
        hipMemsetAsync(d_out, 0, (size_t)N * N_DIM * sizeof(float), stream);
        transpose_w_kernel<<<512, 128, 0, stream>>>(Wq, Wk, Wv, Wo, Wt, Wot);
        qkv_mfma_kernel<<<(N + 31) / 32, 256, 0, stream>>>(
            nodes, Wt, bq, bk, bv, qb, kb, vb, N);
        edge_kernel<<<(E + 3) / 4, 256, 0, stream>>>(
            senders, receivers, qb, kb, vb, out, E);
        out_mfma_kernel<<<(N + 31) / 32, 256, 0, stream>>>(
            nodes, Wot, bo, out, N);
    }
}